// Round 10
// baseline (133.567 us; speedup 1.0000x reference)
//
#include <hip/hip_runtime.h>
#include <hip/hip_bf16.h>

#define KN 256
#define DD 1024
#define HH 2

typedef __attribute__((ext_vector_type(8))) short short8;
typedef __attribute__((ext_vector_type(4))) float f32x4;

__device__ __forceinline__ ushort f2b(float f) {
  union { float f; unsigned u; } v; v.f = f;
  unsigned u = v.u;
  return (ushort)((u + 0x7fffu + ((u >> 16) & 1u)) >> 16);
}
__device__ __forceinline__ float b2f(ushort h) {
  union { unsigned u; float f; } v; v.u = ((unsigned)h) << 16;
  return v.f;
}
__device__ __forceinline__ void gload16(const ushort* g, ushort* l) {
  __builtin_amdgcn_global_load_lds(
      (const __attribute__((address_space(1))) void*)g,
      (__attribute__((address_space(3))) void*)l, 16, 0, 0);
}

// ---------------- K-conv: x f32 -> xb bf16
__global__ __launch_bounds__(256) void k_conv(const float* __restrict__ x,
                                              ushort* __restrict__ xb) {
  int c0 = blockIdx.x * 256 + threadIdx.x;
  for (int it = 0; it < 4; ++it) {
    size_t i = ((size_t)c0 + (size_t)it * 524288) * 8;
    float4 v0 = *reinterpret_cast<const float4*>(&x[i]);
    float4 v1 = *reinterpret_cast<const float4*>(&x[i + 4]);
    short8 o;
    o[0] = (short)f2b(v0.x); o[1] = (short)f2b(v0.y);
    o[2] = (short)f2b(v0.z); o[3] = (short)f2b(v0.w);
    o[4] = (short)f2b(v1.x); o[5] = (short)f2b(v1.y);
    o[6] = (short)f2b(v1.z); o[7] = (short)f2b(v1.w);
    *reinterpret_cast<short8*>(&xb[i]) = o;
  }
}

// ---------------- K0: W (DxD f32) -> WTb (DxD bf16, transposed)
__global__ __launch_bounds__(256) void k_wT(const float* __restrict__ W, ushort* __restrict__ WTb) {
  __shared__ float t[32][33];
  int tx = threadIdx.x, ty = threadIdx.y;
  int x = blockIdx.x * 32 + tx;
  int y0 = blockIdx.y * 32 + ty;
  for (int i = 0; i < 32; i += 8)
    t[ty + i][tx] = W[(size_t)(y0 + i) * DD + x];
  __syncthreads();
  int xo = blockIdx.y * 32 + tx;
  int yo = blockIdx.x * 32 + ty;
  for (int i = 0; i < 32; i += 8)
    WTb[(size_t)(yo + i) * DD + xo] = f2b(t[tx][ty + i]);
}

// ---------------- K1: h = xb @ W -> TRANSPOSED hT[b][d][j]
// 8-phase 256x256 schedule (T2+T3+T4+T5), XCD-bijective 1D grid, BK=64, 8 waves.
__global__ __launch_bounds__(512, 2) void k_gemm_h(const ushort* __restrict__ xb,
                                                   const ushort* __restrict__ WTb,
                                                   ushort* __restrict__ hT) {
  __shared__ ushort As[2][16384];   // [buf][256 rows x 64 k]
  __shared__ ushort Bs[2][16384];
  const int tid = threadIdx.x;
  const int w = tid >> 6, lane = tid & 63;
  // XCD-bijective decode: all 4 bn-blocks of batch b on one XCD (flat%8 = const)
  const int flat = blockIdx.x;
  const int bn = (flat >> 3) & 3;
  const int b  = (flat & 7) + 8 * (flat >> 5);
  const int wm = (w >> 2) * 128, wn = (w & 3) * 64;
  const int r16 = lane & 15, kqi = lane >> 4;
  const ushort* gA0 = xb + (size_t)(b * 256) * DD;
  const ushort* gB0 = WTb + (size_t)(bn * 256) * DD;
  // staging per-thread constants (pre-swizzled source, linear LDS dest)
  const int srow0 = tid >> 3;                        // s=0 row; s=1 row = 64+srow0
  const int scc   = (tid & 7) ^ ((tid >> 3) & 7);    // inverse-swizzled col chunk
  const int sdst0 = (tid & ~63) * 8;                 // elem offset of wave base
  // fragment-read swizzled column chunks
  const int cs0 = (kqi)     ^ (r16 & 7);
  const int cs1 = (kqi + 4) ^ (r16 & 7);
  f32x4 acc[8][4] = {};
  short8 bfv[4][2];

#define STG(ISB, BUF, H, KB)                                                    \
  {                                                                             \
    const ushort* g0_ = (ISB) ? gB0 : gA0;                                      \
    ushort* l0_ = (ISB) ? Bs[BUF] : As[BUF];                                    \
    gload16(g0_ + (size_t)((H) * 128 + srow0) * DD + (KB) + scc * 8,            \
            l0_ + (H) * 8192 + sdst0);                                          \
    gload16(g0_ + (size_t)((H) * 128 + 64 + srow0) * DD + (KB) + scc * 8,       \
            l0_ + (H) * 8192 + 4096 + sdst0);                                   \
  }

#define PHASE(Q, BUF, LOADB, WMODE, STAGE_STMT)                                 \
  {                                                                             \
    short8 af0[2], af1[2];                                                      \
    {                                                                           \
      const ushort* Ab_ = As[BUF];                                              \
      int ra_ = (wm + (Q) * 32 + r16) * 64;                                     \
      int rb_ = (wm + (Q) * 32 + 16 + r16) * 64;                                \
      af0[0] = *(const short8*)(Ab_ + ra_ + cs0 * 8);                           \
      af0[1] = *(const short8*)(Ab_ + ra_ + cs1 * 8);                           \
      af1[0] = *(const short8*)(Ab_ + rb_ + cs0 * 8);                           \
      af1[1] = *(const short8*)(Ab_ + rb_ + cs1 * 8);                           \
    }                                                                           \
    if (LOADB) {                                                                \
      const ushort* Bb_ = Bs[BUF];                                              \
      _Pragma("unroll")                                                         \
      for (int nf = 0; nf < 4; ++nf) {                                          \
        int rn_ = (wn + nf * 16 + r16) * 64;                                    \
        bfv[nf][0] = *(const short8*)(Bb_ + rn_ + cs0 * 8);                     \
        bfv[nf][1] = *(const short8*)(Bb_ + rn_ + cs1 * 8);                     \
      }                                                                         \
    }                                                                           \
    STAGE_STMT;                                                                 \
    __builtin_amdgcn_s_barrier();                                               \
    asm volatile("s_waitcnt lgkmcnt(0)" ::: "memory");                          \
    __builtin_amdgcn_sched_barrier(0);                                          \
    __builtin_amdgcn_s_setprio(1);                                              \
    _Pragma("unroll")                                                           \
    for (int nf = 0; nf < 4; ++nf) {                                            \
      acc[(Q)*2][nf]   = __builtin_amdgcn_mfma_f32_16x16x32_bf16(af0[0], bfv[nf][0], acc[(Q)*2][nf], 0, 0, 0);     \
      acc[(Q)*2+1][nf] = __builtin_amdgcn_mfma_f32_16x16x32_bf16(af1[0], bfv[nf][0], acc[(Q)*2+1][nf], 0, 0, 0);   \
    }                                                                           \
    _Pragma("unroll")                                                           \
    for (int nf = 0; nf < 4; ++nf) {                                            \
      acc[(Q)*2][nf]   = __builtin_amdgcn_mfma_f32_16x16x32_bf16(af0[1], bfv[nf][1], acc[(Q)*2][nf], 0, 0, 0);     \
      acc[(Q)*2+1][nf] = __builtin_amdgcn_mfma_f32_16x16x32_bf16(af1[1], bfv[nf][1], acc[(Q)*2+1][nf], 0, 0, 0);   \
    }                                                                           \
    __builtin_amdgcn_s_setprio(0);                                              \
    __builtin_amdgcn_sched_barrier(0);                                          \
    if ((WMODE) == 1) { asm volatile("s_waitcnt vmcnt(6)" ::: "memory"); }      \
    else if ((WMODE) == 2) { asm volatile("s_waitcnt vmcnt(0)" ::: "memory"); } \
    __builtin_amdgcn_s_barrier();                                               \
  }

  // prologue: tile0 (B0,B1,A0,A1) -> buf0; tile1 (B0,B1,A0) -> buf1
  STG(1, 0, 0, 0) STG(1, 0, 1, 0) STG(0, 0, 0, 0) STG(0, 0, 1, 0)
  STG(1, 1, 0, 64) STG(1, 1, 1, 64) STG(0, 1, 0, 64)
  asm volatile("s_waitcnt vmcnt(6)" ::: "memory");   // tile0 landed (keep 3 halves in flight)
  __builtin_amdgcn_sched_barrier(0);
  __builtin_amdgcn_s_barrier();

  for (int i = 0; i < 8; ++i) {
    const int k1 = i * 128 + 64;
    const int k2 = i * 128 + 128;
    const int k3 = i * 128 + 192;
    const bool s2 = (k2 < 1024), s3 = (k3 < 1024);
    const int wt = (i < 7) ? 1 : 2;   // counted in steady state, full drain at tail
    // half 1: K-tile 2i (buf0)
    PHASE(0, 0, 1, 0,  { STG(0, 1, 1, k1) })                 // stage A1(2i+1)
    PHASE(1, 0, 0, 0,  { if (s2) STG(1, 0, 0, k2) })         // B0(2i+2)
    PHASE(2, 0, 0, 0,  { if (s2) STG(1, 0, 1, k2) })         // B1(2i+2)
    PHASE(3, 0, 0, wt, { if (s2) STG(0, 0, 0, k2) })         // A0(2i+2)
    // half 2: K-tile 2i+1 (buf1)
    PHASE(0, 1, 1, 0,  { if (s2) STG(0, 0, 1, k2) })         // A1(2i+2)
    PHASE(1, 1, 0, 0,  { if (s3) STG(1, 1, 0, k3) })         // B0(2i+3)
    PHASE(2, 1, 0, 0,  { if (s3) STG(1, 1, 1, k3) })         // B1(2i+3)
    PHASE(3, 1, 0, wt, { if (s3) STG(0, 1, 0, k3) })         // A0(2i+3)
  }
#undef PHASE
#undef STG

  // transposed epilogue: 4 acc regs = 4 consecutive j -> one 8B store
  const int g = lane >> 4;
  #pragma unroll
  for (int mf = 0; mf < 8; ++mf) {
    int j0 = wm + mf * 16 + g * 4;
    #pragma unroll
    for (int nf = 0; nf < 4; ++nf) {
      int C = bn * 256 + wn + nf * 16 + r16;
      ushort4 o;
      o.x = f2b(acc[mf][nf][0]); o.y = f2b(acc[mf][nf][1]);
      o.z = f2b(acc[mf][nf][2]); o.w = f2b(acc[mf][nf][3]);
      *reinterpret_cast<ushort4*>(&hT[((size_t)b * DD + C) * KN + j0]) = o;
    }
  }
}

// ---------------- K2: f partials from hT (axpy form). block=(b, dq): 256 d-rows
__global__ __launch_bounds__(256) void k_f(const ushort* __restrict__ hT,
                                           const float* __restrict__ a,
                                           float* __restrict__ fip, float* __restrict__ fjp) {
  __shared__ float als[4][256];
  int b = blockIdx.x, dq = blockIdx.y;
  int tid = threadIdx.x;
  for (int v = 0; v < 4; ++v) als[v][tid] = a[v * DD + dq * 256 + tid];
  __syncthreads();
  const ushort* base = hT + ((size_t)b * DD + dq * 256) * KN + tid;
  float a0 = 0.f, a1 = 0.f, a2 = 0.f, a3 = 0.f;
  #pragma unroll 8
  for (int d = 0; d < 256; ++d) {
    float hv = b2f(base[(size_t)d * KN]);
    a0 += hv * als[0][d];
    a1 += hv * als[1][d];
    a2 += hv * als[2][d];
    a3 += hv * als[3][d];
  }
  size_t o = ((size_t)(dq * 64 + b) * HH) * KN + tid;
  fip[o] = a0;        // head0 src
  fjp[o] = a1;        // head0 dst
  fip[o + KN] = a2;   // head1 src
  fjp[o + KN] = a3;   // head1 dst
}

// ---------------- K3: masked leaky softmax, head-mean -> Pbar bf16 (wave per row)
__global__ __launch_bounds__(256) void k_attn(const float* __restrict__ fip, const float* __restrict__ fjp,
                                              const int* __restrict__ adj, ushort* __restrict__ Pb) {
  int w = threadIdx.x >> 6, l = threadIdx.x & 63;
  int gw = blockIdx.x * 4 + w;
  int b = gw >> 8, i = gw & 255;
  int4 am = *reinterpret_cast<const int4*>(adj + i * KN + l * 4);
  int msk[4] = { am.x, am.y, am.z, am.w };
  float fi0 = 0.f, fi1 = 0.f;
  float fj0[4] = {0.f, 0.f, 0.f, 0.f}, fj1[4] = {0.f, 0.f, 0.f, 0.f};
  for (int dq = 0; dq < 4; ++dq) {
    size_t o = ((size_t)(dq * 64 + b) * HH) * KN;
    fi0 += fip[o + i];
    fi1 += fip[o + KN + i];
    float4 t0 = *reinterpret_cast<const float4*>(&fjp[o + l * 4]);
    float4 t1 = *reinterpret_cast<const float4*>(&fjp[o + KN + l * 4]);
    fj0[0] += t0.x; fj0[1] += t0.y; fj0[2] += t0.z; fj0[3] += t0.w;
    fj1[0] += t1.x; fj1[1] += t1.y; fj1[2] += t1.z; fj1[3] += t1.w;
  }
  float e0[4], e1[4];
  const float NEGINF = -3.0e38f;
  float m0 = NEGINF, m1 = NEGINF;
  for (int e = 0; e < 4; ++e) {
    float v0 = fi0 + fj0[e], v1 = fi1 + fj1[e];
    v0 = v0 >= 0.f ? v0 : 0.2f * v0;
    v1 = v1 >= 0.f ? v1 : 0.2f * v1;
    e0[e] = v0; e1[e] = v1;
    if (msk[e]) { m0 = fmaxf(m0, v0); m1 = fmaxf(m1, v1); }
  }
  for (int off = 1; off < 64; off <<= 1) {
    m0 = fmaxf(m0, __shfl_xor(m0, off));
    m1 = fmaxf(m1, __shfl_xor(m1, off));
  }
  float p0[4], p1[4], s0 = 0.f, s1 = 0.f;
  for (int e = 0; e < 4; ++e) {
    p0[e] = msk[e] ? __expf(e0[e] - m0) : 0.f;
    p1[e] = msk[e] ? __expf(e1[e] - m1) : 0.f;
    s0 += p0[e]; s1 += p1[e];
  }
  for (int off = 1; off < 64; off <<= 1) {
    s0 += __shfl_xor(s0, off);
    s1 += __shfl_xor(s1, off);
  }
  float i0 = s0 > 0.f ? 1.f / s0 : 0.f;
  float i1 = s1 > 0.f ? 1.f / s1 : 0.f;
  ushort4 o;
  o.x = f2b(0.5f * (p0[0] * i0 + p1[0] * i1));
  o.y = f2b(0.5f * (p0[1] * i0 + p1[1] * i1));
  o.z = f2b(0.5f * (p0[2] * i0 + p1[2] * i1));
  o.w = f2b(0.5f * (p0[3] * i0 + p1[3] * i1));
  *reinterpret_cast<ushort4*>(&Pb[((size_t)b * KN + i) * KN + l * 4]) = o;
}

// ---------------- K4: y = Pbar[b] @ h[b] + xb (IN-PLACE bf16 residual) + LN partial stats
// 512 thr, 8 thin waves (64x64), counted-vmcnt depth-2
__global__ __launch_bounds__(512) void k_gemm_o(const ushort* __restrict__ Pb,
                                                const ushort* __restrict__ hT,
                                                ushort* __restrict__ yx,   // in: xb, out: y (same buffer)
                                                float* __restrict__ pstats) {
  __shared__ ushort As[2][8192];   // 256 x 32
  __shared__ ushort Bs[2][4096];   // 128 x 32
  __shared__ float red2[256][2][2];
  const int b = blockIdx.x;
  const int dt = blockIdx.y;       // d-tile 0..7
  const int tid = threadIdx.x;
  const int w = tid >> 6, lane = tid & 63;
  const int wm = (w >> 1) * 64;    // i-offset (0..192)
  const int wn = (w & 1) * 64;     // d-offset within 128
  const int r16 = lane & 15, kqi = lane >> 4;
  const ushort* PbB = Pb + (size_t)b * KN * KN;
  const ushort* hTB = hT + ((size_t)b * DD + dt * 128) * KN;
  f32x4 acc[4][4] = {};
  const int wb = tid & ~63;

  #define OSTAGE(buf, kt)                                                          \
    {                                                                              \
      _Pragma("unroll")                                                            \
      for (int s = 0; s < 2; ++s) {                                                \
        int slot = s * 512 + tid;                                                  \
        int row = slot >> 2, kc = slot & 3;                                        \
        gload16(PbB + (size_t)row * KN + (kt) + kc * 8,                            \
                As[buf] + (size_t)(s * 512 + wb) * 8);                             \
      }                                                                            \
      {                                                                            \
        int row = tid >> 2, kc = tid & 3;                                          \
        gload16(hTB + (size_t)row * KN + (kt) + kc * 8,                            \
                Bs[buf] + (size_t)wb * 8);                                         \
      }                                                                            \
    }

  OSTAGE(0, 0);
  OSTAGE(1, 32);
  for (int it8 = 0; it8 < 8; ++it8) {
    const int cur = it8 & 1;
    if (it8 < 7) asm volatile("s_waitcnt vmcnt(3)" ::: "memory");
    else         asm volatile("s_waitcnt vmcnt(0)" ::: "memory");
    __builtin_amdgcn_s_barrier();
    __builtin_amdgcn_sched_barrier(0);
    const ushort* Ac = As[cur];
    const ushort* Bc = Bs[cur];
    short8 af[4], bf[4];
    #pragma unroll
    for (int mf = 0; mf < 4; ++mf) {
      int row = wm + mf * 16 + r16;
      af[mf] = *reinterpret_cast<const short8*>(Ac + (size_t)row * 32 + kqi * 8);
    }
    #pragma unroll
    for (int nf = 0; nf < 4; ++nf) {
      int row = wn + nf * 16 + r16;
      bf[nf] = *reinterpret_cast<const short8*>(Bc + (size_t)row * 32 + kqi * 8);
    }
    #pragma unroll
    for (int mf = 0; mf < 4; ++mf)
      #pragma unroll
      for (int nf = 0; nf < 4; ++nf)
        acc[mf][nf] = __builtin_amdgcn_mfma_f32_16x16x32_bf16(af[mf], bf[nf], acc[mf][nf], 0, 0, 0);
    __builtin_amdgcn_sched_barrier(0);
    __builtin_amdgcn_s_barrier();
    if (it8 < 6)
      OSTAGE(cur, (it8 + 2) * 32);
  }
  #undef OSTAGE

  // epilogue: in-place residual + per-row partial stats over this block's 128 cols
  const int g = lane >> 4;
  float ps[4][4] = {}, qs[4][4] = {};
  #pragma unroll
  for (int mf = 0; mf < 4; ++mf)
    #pragma unroll
    for (int nf = 0; nf < 4; ++nf) {
      int C = dt * 128 + wn + nf * 16 + r16;
      #pragma unroll
      for (int rr = 0; rr < 4; ++rr) {
        int i = wm + mf * 16 + g * 4 + rr;
        size_t gi = ((size_t)(b * KN + i)) * DD + C;
        float v = acc[mf][nf][rr] + b2f(yx[gi]);
        yx[gi] = f2b(v);
        ps[mf][rr] += v; qs[mf][rr] += v * v;
      }
    }
  #pragma unroll
  for (int off = 1; off < 16; off <<= 1)
    #pragma unroll
    for (int mf = 0; mf < 4; ++mf)
      #pragma unroll
      for (int rr = 0; rr < 4; ++rr) {
        ps[mf][rr] += __shfl_xor(ps[mf][rr], off);
        qs[mf][rr] += __shfl_xor(qs[mf][rr], off);
      }
  if (r16 == 0) {
    #pragma unroll
    for (int mf = 0; mf < 4; ++mf)
      #pragma unroll
      for (int rr = 0; rr < 4; ++rr) {
        int i = wm + mf * 16 + g * 4 + rr;
        red2[i][w & 1][0] = ps[mf][rr];
        red2[i][w & 1][1] = qs[mf][rr];
      }
  }
  __syncthreads();
  if (tid < 256) {
    float S = red2[tid][0][0] + red2[tid][1][0];
    float Q = red2[tid][0][1] + red2[tid][1][1];
    size_t o = ((size_t)(dt * 64 + b) * KN + tid) * 2;
    pstats[o] = S;
    pstats[o + 1] = Q;
  }
}

// ---------------- K5: LN scale pass: out = (y - mu) * inv * gamma + beta
__global__ __launch_bounds__(256) void k_ln(const ushort* __restrict__ y,
                                            const float* __restrict__ pstats,
                                            const float* __restrict__ gamma,
                                            const float* __restrict__ beta,
                                            float* __restrict__ out) {
  int tid = threadIdx.x;
  size_t row = blockIdx.x;
  int b = (int)(row >> 8), i = (int)(row & 255);
  float S = 0.f, Q = 0.f;
  #pragma unroll
  for (int dt = 0; dt < 8; ++dt) {
    size_t o = ((size_t)(dt * 64 + b) * KN + i) * 2;
    S += pstats[o];
    Q += pstats[o + 1];
  }
  float mu = S * (1.0f / DD);
  float var = Q * (1.0f / DD) - mu * mu;
  float inv = rsqrtf(var + 1e-5f);
  ushort4 v = *reinterpret_cast<const ushort4*>(&y[row * DD + tid * 4]);
  float4 gm = *reinterpret_cast<const float4*>(&gamma[tid * 4]);
  float4 bt = *reinterpret_cast<const float4*>(&beta[tid * 4]);
  float4 o;
  o.x = (b2f(v.x) - mu) * inv * gm.x + bt.x;
  o.y = (b2f(v.y) - mu) * inv * gm.y + bt.y;
  o.z = (b2f(v.z) - mu) * inv * gm.z + bt.z;
  o.w = (b2f(v.w) - mu) * inv * gm.w + bt.w;
  *reinterpret_cast<float4*>(&out[row * DD + tid * 4]) = o;
}

extern "C" void kernel_launch(void* const* d_in, const int* in_sizes, int n_in,
                              void* d_out, int out_size, void* d_ws, size_t ws_size,
                              hipStream_t stream) {
  const float* x     = (const float*)d_in[0];
  const int*   adj   = (const int*)d_in[1];
  const float* W     = (const float*)d_in[2];
  const float* a     = (const float*)d_in[3];
  const float* gamma = (const float*)d_in[4];
  const float* beta  = (const float*)d_in[5];
  float* out = (float*)d_out;

  char* ws = (char*)d_ws;
  // Layout (NEED = 77856768):
  //   [0, 2M):      WTb (wT->gemm_h); then fip [0,512K) + fjp [512K,1M) (k_f->attn);
  //                 then pstats (gemm_o->ln)
  //   [2M, 35.5M):  xb (conv->gemm_h); gemm_o in-place residual -> y; k_ln reads
  //   [35.5M, 69M): hT (gemm_h->gemm_o)
  //   [69M, 77.4M): Pb (attn->gemm_o)
  const size_t OFS_WT = 0;
  const size_t OFS_XB = 2097152;
  const size_t OFS_HT = 35651584;
  const size_t OFS_PB = 69206016;
  const size_t NEED   = 77856768;
  if (ws_size < NEED) return;

  ushort* WTb   = (ushort*)(ws + OFS_WT);
  float*  fip   = (float*)(ws + OFS_WT);            // after WTb dead
  float*  fjp   = (float*)(ws + OFS_WT + 524288);
  float*  pst   = (float*)(ws + OFS_WT);            // after fip/fjp dead
  ushort* xb    = (ushort*)(ws + OFS_XB);           // xb, then y in-place
  ushort* hT    = (ushort*)(ws + OFS_HT);
  ushort* Pb    = (ushort*)(ws + OFS_PB);

  k_conv<<<2048, 256, 0, stream>>>(x, xb);
  k_wT<<<dim3(32, 32), dim3(32, 8), 0, stream>>>(W, WTb);
  k_gemm_h<<<256, 512, 0, stream>>>(xb, WTb, hT);
  k_f<<<dim3(64, 4), 256, 0, stream>>>(hT, a, fip, fjp);
  k_attn<<<4096, 256, 0, stream>>>(fip, fjp, adj, Pb);
  k_gemm_o<<<dim3(64, 8), 512, 0, stream>>>(Pb, hT, xb, pst);
  k_ln<<<16384, 256, 0, stream>>>(xb, pst, gamma, beta, out);
}

// Round 12
// 119.367 us; speedup vs baseline: 1.1190x; 1.1190x over previous
//
#include <hip/hip_runtime.h>
#include <hip/hip_bf16.h>

#define KN 256
#define DD 1024
#define HH 2

typedef __attribute__((ext_vector_type(8))) short short8;
typedef __attribute__((ext_vector_type(4))) float f32x4;

__device__ __forceinline__ ushort f2b(float f) {
  union { float f; unsigned u; } v; v.f = f;
  unsigned u = v.u;
  return (ushort)((u + 0x7fffu + ((u >> 16) & 1u)) >> 16);
}
__device__ __forceinline__ float b2f(ushort h) {
  union { unsigned u; float f; } v; v.u = ((unsigned)h) << 16;
  return v.f;
}
__device__ __forceinline__ void gload16(const ushort* g, ushort* l) {
  __builtin_amdgcn_global_load_lds(
      (const __attribute__((address_space(1))) void*)g,
      (__attribute__((address_space(3))) void*)l, 16, 0, 0);
}

// ---------------- K-prep: blocks [0,2048) = x f32 -> xb bf16; [2048,3072) = W -> WTb transposed
__global__ __launch_bounds__(256) void k_prep(const float* __restrict__ x,
                                              ushort* __restrict__ xb,
                                              const float* __restrict__ W,
                                              ushort* __restrict__ WTb) {
  int bid = blockIdx.x, tid = threadIdx.x;
  if (bid < 2048) {
    int c0 = bid * 256 + tid;
    for (int it = 0; it < 4; ++it) {
      size_t i = ((size_t)c0 + (size_t)it * 524288) * 8;
      float4 v0 = *reinterpret_cast<const float4*>(&x[i]);
      float4 v1 = *reinterpret_cast<const float4*>(&x[i + 4]);
      short8 o;
      o[0] = (short)f2b(v0.x); o[1] = (short)f2b(v0.y);
      o[2] = (short)f2b(v0.z); o[3] = (short)f2b(v0.w);
      o[4] = (short)f2b(v1.x); o[5] = (short)f2b(v1.y);
      o[6] = (short)f2b(v1.z); o[7] = (short)f2b(v1.w);
      *reinterpret_cast<short8*>(&xb[i]) = o;
    }
  } else {
    __shared__ float t[32][33];
    int wb = bid - 2048;
    int bx = wb & 31, by = wb >> 5;
    int tx = tid & 31, ty = tid >> 5;
    int xx = bx * 32 + tx;
    int y0 = by * 32 + ty;
    for (int i = 0; i < 32; i += 8)
      t[ty + i][tx] = W[(size_t)(y0 + i) * DD + xx];
    __syncthreads();
    int xo = by * 32 + tx;
    int yo = bx * 32 + ty;
    for (int i = 0; i < 32; i += 8)
      WTb[(size_t)(yo + i) * DD + xo] = f2b(t[tx][ty + i]);
  }
}

// ---------------- K1: h = xb @ W -> TRANSPOSED hT[b][d][j]
// 8-phase 256x256 schedule (T2+T3+T4+T5), XCD-bijective 1D grid, BK=64, 8 waves.
__global__ __launch_bounds__(512, 2) void k_gemm_h(const ushort* __restrict__ xb,
                                                   const ushort* __restrict__ WTb,
                                                   ushort* __restrict__ hT) {
  __shared__ ushort As[2][16384];   // [buf][256 rows x 64 k]
  __shared__ ushort Bs[2][16384];
  const int tid = threadIdx.x;
  const int w = tid >> 6, lane = tid & 63;
  // XCD-bijective decode: all 4 bn-blocks of batch b on one XCD (flat%8 = const)
  const int flat = blockIdx.x;
  const int bn = (flat >> 3) & 3;
  const int b  = (flat & 7) + 8 * (flat >> 5);
  const int wm = (w >> 2) * 128, wn = (w & 3) * 64;
  const int r16 = lane & 15, kqi = lane >> 4;
  const ushort* gA0 = xb + (size_t)(b * 256) * DD;
  const ushort* gB0 = WTb + (size_t)(bn * 256) * DD;
  // staging per-thread constants (pre-swizzled source, linear LDS dest)
  const int srow0 = tid >> 3;                        // s=0 row; s=1 row = 64+srow0
  const int scc   = (tid & 7) ^ ((tid >> 3) & 7);    // inverse-swizzled col chunk
  const int sdst0 = (tid & ~63) * 8;                 // elem offset of wave base
  // fragment-read swizzled column chunks
  const int cs0 = (kqi)     ^ (r16 & 7);
  const int cs1 = (kqi + 4) ^ (r16 & 7);
  f32x4 acc[8][4] = {};
  short8 bfv[4][2];

#define STG(ISB, BUF, H, KB)                                                    \
  {                                                                             \
    const ushort* g0_ = (ISB) ? gB0 : gA0;                                      \
    ushort* l0_ = (ISB) ? Bs[BUF] : As[BUF];                                    \
    gload16(g0_ + (size_t)((H) * 128 + srow0) * DD + (KB) + scc * 8,            \
            l0_ + (H) * 8192 + sdst0);                                          \
    gload16(g0_ + (size_t)((H) * 128 + 64 + srow0) * DD + (KB) + scc * 8,       \
            l0_ + (H) * 8192 + 4096 + sdst0);                                   \
  }

#define PHASE(Q, BUF, LOADB, WMODE, STAGE_STMT)                                 \
  {                                                                             \
    short8 af0[2], af1[2];                                                      \
    {                                                                           \
      const ushort* Ab_ = As[BUF];                                              \
      int ra_ = (wm + (Q) * 32 + r16) * 64;                                     \
      int rb_ = (wm + (Q) * 32 + 16 + r16) * 64;                                \
      af0[0] = *(const short8*)(Ab_ + ra_ + cs0 * 8);                           \
      af0[1] = *(const short8*)(Ab_ + ra_ + cs1 * 8);                           \
      af1[0] = *(const short8*)(Ab_ + rb_ + cs0 * 8);                           \
      af1[1] = *(const short8*)(Ab_ + rb_ + cs1 * 8);                           \
    }                                                                           \
    if (LOADB) {                                                                \
      const ushort* Bb_ = Bs[BUF];                                              \
      _Pragma("unroll")                                                         \
      for (int nf = 0; nf < 4; ++nf) {                                          \
        int rn_ = (wn + nf * 16 + r16) * 64;                                    \
        bfv[nf][0] = *(const short8*)(Bb_ + rn_ + cs0 * 8);                     \
        bfv[nf][1] = *(const short8*)(Bb_ + rn_ + cs1 * 8);                     \
      }                                                                         \
    }                                                                           \
    STAGE_STMT;                                                                 \
    __builtin_amdgcn_s_barrier();                                               \
    asm volatile("s_waitcnt lgkmcnt(0)" ::: "memory");                          \
    __builtin_amdgcn_sched_barrier(0);                                          \
    __builtin_amdgcn_s_setprio(1);                                              \
    _Pragma("unroll")                                                           \
    for (int nf = 0; nf < 4; ++nf) {                                            \
      acc[(Q)*2][nf]   = __builtin_amdgcn_mfma_f32_16x16x32_bf16(af0[0], bfv[nf][0], acc[(Q)*2][nf], 0, 0, 0);     \
      acc[(Q)*2+1][nf] = __builtin_amdgcn_mfma_f32_16x16x32_bf16(af1[0], bfv[nf][0], acc[(Q)*2+1][nf], 0, 0, 0);   \
    }                                                                           \
    _Pragma("unroll")                                                           \
    for (int nf = 0; nf < 4; ++nf) {                                            \
      acc[(Q)*2][nf]   = __builtin_amdgcn_mfma_f32_16x16x32_bf16(af0[1], bfv[nf][1], acc[(Q)*2][nf], 0, 0, 0);     \
      acc[(Q)*2+1][nf] = __builtin_amdgcn_mfma_f32_16x16x32_bf16(af1[1], bfv[nf][1], acc[(Q)*2+1][nf], 0, 0, 0);   \
    }                                                                           \
    __builtin_amdgcn_s_setprio(0);                                              \
    __builtin_amdgcn_sched_barrier(0);                                          \
    if ((WMODE) == 1) { asm volatile("s_waitcnt vmcnt(6)" ::: "memory"); }      \
    else if ((WMODE) == 2) { asm volatile("s_waitcnt vmcnt(0)" ::: "memory"); } \
    __builtin_amdgcn_s_barrier();                                               \
  }

  // prologue: tile0 (B0,B1,A0,A1) -> buf0; tile1 (B0,B1,A0) -> buf1
  STG(1, 0, 0, 0) STG(1, 0, 1, 0) STG(0, 0, 0, 0) STG(0, 0, 1, 0)
  STG(1, 1, 0, 64) STG(1, 1, 1, 64) STG(0, 1, 0, 64)
  asm volatile("s_waitcnt vmcnt(6)" ::: "memory");   // tile0 landed (keep 3 halves in flight)
  __builtin_amdgcn_sched_barrier(0);
  __builtin_amdgcn_s_barrier();

  for (int i = 0; i < 8; ++i) {
    const int k1 = i * 128 + 64;
    const int k2 = i * 128 + 128;
    const int k3 = i * 128 + 192;
    const bool s2 = (k2 < 1024), s3 = (k3 < 1024);
    const int wt = (i < 7) ? 1 : 2;   // counted in steady state, full drain at tail
    // half 1: K-tile 2i (buf0)
    PHASE(0, 0, 1, 0,  { STG(0, 1, 1, k1) })                 // stage A1(2i+1)
    PHASE(1, 0, 0, 0,  { if (s2) STG(1, 0, 0, k2) })         // B0(2i+2)
    PHASE(2, 0, 0, 0,  { if (s2) STG(1, 0, 1, k2) })         // B1(2i+2)
    PHASE(3, 0, 0, wt, { if (s2) STG(0, 0, 0, k2) })         // A0(2i+2)
    // half 2: K-tile 2i+1 (buf1)
    PHASE(0, 1, 1, 0,  { if (s2) STG(0, 0, 1, k2) })         // A1(2i+2)
    PHASE(1, 1, 0, 0,  { if (s3) STG(1, 1, 0, k3) })         // B0(2i+3)
    PHASE(2, 1, 0, 0,  { if (s3) STG(1, 1, 1, k3) })         // B1(2i+3)
    PHASE(3, 1, 0, wt, { if (s3) STG(0, 1, 0, k3) })         // A0(2i+3)
  }
#undef PHASE
#undef STG

  // transposed epilogue: 4 acc regs = 4 consecutive j -> one 8B store
  const int g = lane >> 4;
  #pragma unroll
  for (int mf = 0; mf < 8; ++mf) {
    int j0 = wm + mf * 16 + g * 4;
    #pragma unroll
    for (int nf = 0; nf < 4; ++nf) {
      int C = bn * 256 + wn + nf * 16 + r16;
      ushort4 o;
      o.x = f2b(acc[mf][nf][0]); o.y = f2b(acc[mf][nf][1]);
      o.z = f2b(acc[mf][nf][2]); o.w = f2b(acc[mf][nf][3]);
      *reinterpret_cast<ushort4*>(&hT[((size_t)b * DD + C) * KN + j0]) = o;
    }
  }
}

// ---------------- K2: f partials from hT (axpy form). block=(b, dq): 256 d-rows
__global__ __launch_bounds__(256) void k_f(const ushort* __restrict__ hT,
                                           const float* __restrict__ a,
                                           float* __restrict__ fip, float* __restrict__ fjp) {
  __shared__ float als[4][256];
  int b = blockIdx.x, dq = blockIdx.y;
  int tid = threadIdx.x;
  for (int v = 0; v < 4; ++v) als[v][tid] = a[v * DD + dq * 256 + tid];
  __syncthreads();
  const ushort* base = hT + ((size_t)b * DD + dq * 256) * KN + tid;
  float a0 = 0.f, a1 = 0.f, a2 = 0.f, a3 = 0.f;
  #pragma unroll 8
  for (int d = 0; d < 256; ++d) {
    float hv = b2f(base[(size_t)d * KN]);
    a0 += hv * als[0][d];
    a1 += hv * als[1][d];
    a2 += hv * als[2][d];
    a3 += hv * als[3][d];
  }
  size_t o = ((size_t)(dq * 64 + b) * HH) * KN + tid;
  fip[o] = a0;        // head0 src
  fjp[o] = a1;        // head0 dst
  fip[o + KN] = a2;   // head1 src
  fjp[o + KN] = a3;   // head1 dst
}

// ---------------- K3: masked leaky softmax, head-mean -> Pbar bf16 (wave per row)
__global__ __launch_bounds__(256) void k_attn(const float* __restrict__ fip, const float* __restrict__ fjp,
                                              const int* __restrict__ adj, ushort* __restrict__ Pb) {
  int w = threadIdx.x >> 6, l = threadIdx.x & 63;
  int gw = blockIdx.x * 4 + w;
  int b = gw >> 8, i = gw & 255;
  int4 am = *reinterpret_cast<const int4*>(adj + i * KN + l * 4);
  int msk[4] = { am.x, am.y, am.z, am.w };
  float fi0 = 0.f, fi1 = 0.f;
  float fj0[4] = {0.f, 0.f, 0.f, 0.f}, fj1[4] = {0.f, 0.f, 0.f, 0.f};
  for (int dq = 0; dq < 4; ++dq) {
    size_t o = ((size_t)(dq * 64 + b) * HH) * KN;
    fi0 += fip[o + i];
    fi1 += fip[o + KN + i];
    float4 t0 = *reinterpret_cast<const float4*>(&fjp[o + l * 4]);
    float4 t1 = *reinterpret_cast<const float4*>(&fjp[o + KN + l * 4]);
    fj0[0] += t0.x; fj0[1] += t0.y; fj0[2] += t0.z; fj0[3] += t0.w;
    fj1[0] += t1.x; fj1[1] += t1.y; fj1[2] += t1.z; fj1[3] += t1.w;
  }
  float e0[4], e1[4];
  const float NEGINF = -3.0e38f;
  float m0 = NEGINF, m1 = NEGINF;
  for (int e = 0; e < 4; ++e) {
    float v0 = fi0 + fj0[e], v1 = fi1 + fj1[e];
    v0 = v0 >= 0.f ? v0 : 0.2f * v0;
    v1 = v1 >= 0.f ? v1 : 0.2f * v1;
    e0[e] = v0; e1[e] = v1;
    if (msk[e]) { m0 = fmaxf(m0, v0); m1 = fmaxf(m1, v1); }
  }
  for (int off = 1; off < 64; off <<= 1) {
    m0 = fmaxf(m0, __shfl_xor(m0, off));
    m1 = fmaxf(m1, __shfl_xor(m1, off));
  }
  float p0[4], p1[4], s0 = 0.f, s1 = 0.f;
  for (int e = 0; e < 4; ++e) {
    p0[e] = msk[e] ? __expf(e0[e] - m0) : 0.f;
    p1[e] = msk[e] ? __expf(e1[e] - m1) : 0.f;
    s0 += p0[e]; s1 += p1[e];
  }
  for (int off = 1; off < 64; off <<= 1) {
    s0 += __shfl_xor(s0, off);
    s1 += __shfl_xor(s1, off);
  }
  float i0 = s0 > 0.f ? 1.f / s0 : 0.f;
  float i1 = s1 > 0.f ? 1.f / s1 : 0.f;
  ushort4 o;
  o.x = f2b(0.5f * (p0[0] * i0 + p1[0] * i1));
  o.y = f2b(0.5f * (p0[1] * i0 + p1[1] * i1));
  o.z = f2b(0.5f * (p0[2] * i0 + p1[2] * i1));
  o.w = f2b(0.5f * (p0[3] * i0 + p1[3] * i1));
  *reinterpret_cast<ushort4*>(&Pb[((size_t)b * KN + i) * KN + l * 4]) = o;
}

// ---------------- K4: out = LN(Pbar[b] @ h[b] + xb) -- full-row blocks, no cross-block sync
// block = (b, itile): 32 rows x 1024 cols, K=256, BK=32, depth-2 counted vmcnt(9).
// XCD-bijective: all 8 itile-blocks of batch b on one XCD -> hT[b] L2-resident.
__global__ __launch_bounds__(512) void k_gemm_o_ln(const ushort* __restrict__ Pb,
                                                   const ushort* __restrict__ hT,
                                                   const ushort* __restrict__ xb,
                                                   const float* __restrict__ gamma,
                                                   const float* __restrict__ beta,
                                                   float* __restrict__ out) {
  __shared__ ushort As[2][1024];    // 32 x 32
  __shared__ ushort Bs[2][32768];   // 1024 x 32
  __shared__ float red[32][8][2];
  const int tid = threadIdx.x;
  const int w = tid >> 6, lane = tid & 63;
  const int flat = blockIdx.x;
  const int itile = (flat >> 3) & 7;
  const int b = (flat & 7) + 8 * (flat >> 6);
  const int wn = w * 128;
  const int r16 = lane & 15, kqi = lane >> 4, g = lane >> 4;
  const ushort* PbB = Pb + ((size_t)b * KN + itile * 32) * KN;
  const ushort* hTB = hT + (size_t)b * DD * KN;
  f32x4 acc[2][8] = {};
  const int wb = tid & ~63;

  // 9 VMEM instrs per wave per stage (8 B + 1 exec-masked A) -> uniform vmcnt
  #define OSTAGE(buf, kt)                                                          \
    {                                                                              \
      _Pragma("unroll")                                                            \
      for (int s = 0; s < 8; ++s) {                                                \
        int c = s * 512 + tid;                                                     \
        int row = c >> 2, kc = c & 3;                                              \
        int kcs = kc ^ ((row >> 1) & 3);                                           \
        gload16(hTB + (size_t)row * KN + (kt) + kcs * 8,                           \
                Bs[buf] + (size_t)(s * 512 + wb) * 8);                             \
      }                                                                            \
      {                                                                            \
        int c = w * 16 + lane;                                                     \
        int row = c >> 2, kc = c & 3;                                              \
        int kcs = kc ^ ((row >> 1) & 3);                                           \
        if (lane < 16)                                                             \
          gload16(PbB + (size_t)row * KN + (kt) + kcs * 8, As[buf] + w * 128);     \
      }                                                                            \
    }

  OSTAGE(0, 0);
  OSTAGE(1, 32);
  for (int it = 0; it < 8; ++it) {
    const int cur = it & 1;
    if (it < 7) asm volatile("s_waitcnt vmcnt(9)" ::: "memory");
    else        asm volatile("s_waitcnt vmcnt(0)" ::: "memory");
    __builtin_amdgcn_s_barrier();
    __builtin_amdgcn_sched_barrier(0);
    const ushort* Ac = As[cur];
    const ushort* Bc = Bs[cur];
    short8 af[2];
    #pragma unroll
    for (int mf = 0; mf < 2; ++mf) {
      int row = mf * 16 + r16;
      af[mf] = *reinterpret_cast<const short8*>(Ac + row * 32 + (kqi ^ ((row >> 1) & 3)) * 8);
    }
    #pragma unroll
    for (int nf = 0; nf < 8; ++nf) {
      int row = wn + nf * 16 + r16;
      short8 bf = *reinterpret_cast<const short8*>(Bc + (size_t)row * 32 + (kqi ^ ((row >> 1) & 3)) * 8);
      acc[0][nf] = __builtin_amdgcn_mfma_f32_16x16x32_bf16(af[0], bf, acc[0][nf], 0, 0, 0);
      acc[1][nf] = __builtin_amdgcn_mfma_f32_16x16x32_bf16(af[1], bf, acc[1][nf], 0, 0, 0);
    }
    __builtin_amdgcn_sched_barrier(0);
    __builtin_amdgcn_s_barrier();
    if (it < 6)
      OSTAGE(cur, (it + 2) * 32);
  }
  #undef OSTAGE

  // epilogue: residual + per-row stats (fully in-block: rows complete) + LN + out
  float ps[2][4] = {}, qs[2][4] = {};
  #pragma unroll
  for (int mf = 0; mf < 2; ++mf)
    #pragma unroll
    for (int nf = 0; nf < 8; ++nf) {
      int col = wn + nf * 16 + r16;
      #pragma unroll
      for (int rr = 0; rr < 4; ++rr) {
        int row = mf * 16 + g * 4 + rr;
        size_t gi = ((size_t)(b * KN + itile * 32 + row)) * DD + col;
        float v = acc[mf][nf][rr] + b2f(xb[gi]);
        acc[mf][nf][rr] = v;
        ps[mf][rr] += v; qs[mf][rr] += v * v;
      }
    }
  #pragma unroll
  for (int off = 1; off < 16; off <<= 1)
    #pragma unroll
    for (int mf = 0; mf < 2; ++mf)
      #pragma unroll
      for (int rr = 0; rr < 4; ++rr) {
        ps[mf][rr] += __shfl_xor(ps[mf][rr], off);
        qs[mf][rr] += __shfl_xor(qs[mf][rr], off);
      }
  if (r16 == 0) {
    #pragma unroll
    for (int mf = 0; mf < 2; ++mf)
      #pragma unroll
      for (int rr = 0; rr < 4; ++rr) {
        int row = mf * 16 + g * 4 + rr;
        red[row][w][0] = ps[mf][rr];
        red[row][w][1] = qs[mf][rr];
      }
  }
  __syncthreads();
  float mu_[2][4], inv_[2][4];
  #pragma unroll
  for (int mf = 0; mf < 2; ++mf)
    #pragma unroll
    for (int rr = 0; rr < 4; ++rr) {
      int row = mf * 16 + g * 4 + rr;
      float S = 0.f, Q = 0.f;
      #pragma unroll
      for (int wv = 0; wv < 8; ++wv) { S += red[row][wv][0]; Q += red[row][wv][1]; }
      float m = S * (1.0f / DD);
      float var = Q * (1.0f / DD) - m * m;
      mu_[mf][rr] = m;
      inv_[mf][rr] = rsqrtf(var + 1e-5f);
    }
  #pragma unroll
  for (int nf = 0; nf < 8; ++nf) {
    int col = wn + nf * 16 + r16;
    float gm = gamma[col], bt = beta[col];
    #pragma unroll
    for (int mf = 0; mf < 2; ++mf)
      #pragma unroll
      for (int rr = 0; rr < 4; ++rr) {
        int row = mf * 16 + g * 4 + rr;
        size_t gi = ((size_t)(b * KN + itile * 32 + row)) * DD + col;
        out[gi] = (acc[mf][nf][rr] - mu_[mf][rr]) * inv_[mf][rr] * gm + bt;
      }
  }
}

extern "C" void kernel_launch(void* const* d_in, const int* in_sizes, int n_in,
                              void* d_out, int out_size, void* d_ws, size_t ws_size,
                              hipStream_t stream) {
  const float* x     = (const float*)d_in[0];
  const int*   adj   = (const int*)d_in[1];
  const float* W     = (const float*)d_in[2];
  const float* a     = (const float*)d_in[3];
  const float* gamma = (const float*)d_in[4];
  const float* beta  = (const float*)d_in[5];
  float* out = (float*)d_out;

  char* ws = (char*)d_ws;
  // Layout (NEED = 77856768):
  //   [0, 2M):      WTb (prep->gemm_h); then fip [0,512K) + fjp [512K,1M) (k_f->attn)
  //   [2M, 35.5M):  xb (prep->gemm_h, gemm_o_ln residual; read-only after prep)
  //   [35.5M, 69M): hT (gemm_h->k_f, gemm_o_ln)
  //   [69M, 77.4M): Pb (attn->gemm_o_ln)
  const size_t OFS_WT = 0;
  const size_t OFS_XB = 2097152;
  const size_t OFS_HT = 35651584;
  const size_t OFS_PB = 69206016;
  const size_t NEED   = 77856768;
  if (ws_size < NEED) return;

  ushort* WTb   = (ushort*)(ws + OFS_WT);
  float*  fip   = (float*)(ws + OFS_WT);            // after WTb dead
  float*  fjp   = (float*)(ws + OFS_WT + 524288);
  ushort* xb    = (ushort*)(ws + OFS_XB);
  ushort* hT    = (ushort*)(ws + OFS_HT);
  ushort* Pb    = (ushort*)(ws + OFS_PB);

  k_prep<<<3072, 256, 0, stream>>>(x, xb, W, WTb);
  k_gemm_h<<<256, 512, 0, stream>>>(xb, WTb, hT);
  k_f<<<dim3(64, 4), 256, 0, stream>>>(hT, a, fip, fjp);
  k_attn<<<4096, 256, 0, stream>>>(fip, fjp, adj, Pb);
  k_gemm_o_ln<<<512, 512, 0, stream>>>(Pb, hT, xb, gamma, beta, out);
}